// Round 7
// baseline (498.084 us; speedup 1.0000x reference)
//
#include <hip/hip_runtime.h>
#include <math.h>

#define NN 50000
#define NE 400000

typedef __attribute__((ext_vector_type(8))) short bf16x8;
typedef __attribute__((ext_vector_type(4))) float f32x4;
typedef unsigned short ushort_t;

__device__ __forceinline__ unsigned short f2bf(float f) {
    unsigned int u = __float_as_uint(f);
    u += 0x7FFF + ((u >> 16) & 1);   // RNE
    return (unsigned short)(u >> 16);
}
__device__ __forceinline__ float2 upk(unsigned int w) {
    float2 r;
    r.x = __uint_as_float(w << 16);
    r.y = __uint_as_float(w & 0xFFFF0000u);
    return r;
}

#define LOG2E 1.4426950408889634f
#define LN2   0.6931471805599453f

// msg = sigmoid(gf)*softplus(gs) via raw v_exp_f32/v_log_f32/v_rcp_f32.
// Valid since |g| << 127: exp2 cannot overflow, both tails exact in fp32.
__device__ __forceinline__ float msg_act(float gf, float gs) {
    float tf = __builtin_amdgcn_exp2f(gf * -LOG2E);
    float sig = __builtin_amdgcn_rcpf(1.0f + tf) * LN2;   // sigmoid * ln2
    float ts = __builtin_amdgcn_exp2f(gs * LOG2E);
    float lg = __builtin_amdgcn_logf(1.0f + ts);          // log2(1+2^(s*log2e))
    return sig * lg;
}

// WT[512][128]: row c = output col, contiguous k. cols 0-127 Wf(dst), 128-255 Wf(src),
// 256-383 Ws(dst), 384-511 Ws(src). WeT[256][64] same for edge part. bcat=[bf|bs].
__global__ void pack_weights(const float* __restrict__ Wf, const float* __restrict__ bf,
                             const float* __restrict__ Ws, const float* __restrict__ bs,
                             ushort_t* __restrict__ WT, ushort_t* __restrict__ WeT,
                             float* __restrict__ bcat) {
    int i = blockIdx.x * 256 + threadIdx.x;
    if (i < 512 * 128) {
        int c = i >> 7, k = i & 127;
        float w;
        if (c < 128)      w = Wf[k * 128 + c];
        else if (c < 256) w = Wf[(128 + k) * 128 + (c - 128)];
        else if (c < 384) w = Ws[k * 128 + (c - 256)];
        else              w = Ws[(128 + k) * 128 + (c - 384)];
        WT[i] = f2bf(w);
    } else if (i < 512 * 128 + 256 * 64) {
        int j = i - 512 * 128;
        int c = j >> 6, k = j & 63;
        float w = (c < 128) ? Wf[(256 + k) * 128 + c] : Ws[(256 + k) * 128 + (c - 128)];
        WeT[j] = f2bf(w);
    } else if (i < 512 * 128 + 256 * 64 + 256) {
        int c = i - (512 * 128 + 256 * 64);
        bcat[c] = (c < 128) ? bf[c] : bs[c - 128];
    }
}

// fp32 -> bf16 bulk convert, 8 elems/thread
__global__ void cvt_bf16(const float* __restrict__ in, ushort_t* __restrict__ out, int n8) {
    int i = blockIdx.x * 256 + threadIdx.x;
    if (i >= n8) return;
    const float4* p = (const float4*)in + (size_t)i * 2;
    float4 a = p[0], b = p[1];
    bf16x8 v;
    v[0] = (short)f2bf(a.x); v[1] = (short)f2bf(a.y);
    v[2] = (short)f2bf(a.z); v[3] = (short)f2bf(a.w);
    v[4] = (short)f2bf(b.x); v[5] = (short)f2bf(b.y);
    v[6] = (short)f2bf(b.z); v[7] = (short)f2bf(b.w);
    *((bf16x8*)out + i) = v;
}

// P[NN][512] (bf16) = hb[NN][128] (bf16) @ W. Grid (ceil(NN/64), 4); 4 waves/block.
__global__ __launch_bounds__(256) void node_gemm(const ushort_t* __restrict__ hb,
                                                 const ushort_t* __restrict__ WT,
                                                 ushort_t* __restrict__ P) {
    __shared__ ushort_t Bs[128 * 136];
    const int tid = threadIdx.x;
    const int w = tid >> 6, l = tid & 63;
    const int by = blockIdx.y;
    const ushort_t* src = WT + (size_t)by * 128 * 128;
    #pragma unroll
    for (int j = 0; j < 8; ++j) {
        int cid = j * 256 + tid;            // 2048 chunks of 8 bf16
        int row = cid >> 4, off = (cid & 15) * 8;
        *(bf16x8*)(&Bs[row * 136 + off]) = *(const bf16x8*)(src + row * 128 + off);
    }
    __syncthreads();
    const int r0 = blockIdx.x * 64 + w * 16;
    const int lrow = l & 15, lk = l >> 4;
    int arow = r0 + lrow;
    if (arow >= NN) arow = NN - 1;
    f32x4 acc[8];
    #pragma unroll
    for (int i = 0; i < 8; ++i) acc[i] = (f32x4){0.f, 0.f, 0.f, 0.f};
    #pragma unroll
    for (int ks = 0; ks < 4; ++ks) {
        int kb = ks * 32 + lk * 8;
        bf16x8 af = *(const bf16x8*)(hb + (size_t)arow * 128 + kb);
        #pragma unroll
        for (int nc = 0; nc < 8; ++nc) {
            bf16x8 bfr = *(const bf16x8*)(&Bs[(nc * 16 + lrow) * 136 + kb]);
            acc[nc] = __builtin_amdgcn_mfma_f32_16x16x32_bf16(af, bfr, acc[nc], 0, 0, 0);
        }
    }
    const int rb = r0 + lk * 4;
    const int cb = by * 128;
    #pragma unroll
    for (int nc = 0; nc < 8; ++nc) {
        int col = cb + nc * 16 + lrow;
        #pragma unroll
        for (int r = 0; r < 4; ++r) {
            int row = rb + r;
            if (row < NN) P[(size_t)row * 512 + col] = f2bf(acc[nc][r]);
        }
    }
}

// Fused: 512 threads / block = 8 waves; block owns 64 consecutive edges.
// Phase 1: wave-pair (tile = w>>1, half = w&1) computes Q[tile*16..+16][half*128..+128]
//          = eab @ We + b via 8 MFMAs -> LDS (bf16, rows padded to 264).
// Phase 2: wave w handles edges w*8..w*8+7, HALF-WAVE per edge (32 lanes x 4 cols
//          via uint2), 2 edges/iter x 4 iters. All global loads issued before any
//          compute (issue-all-then-compute) so gather latencies overlap.
__global__ __launch_bounds__(512, 4) void edge_fused(const int* __restrict__ ei,
                                                     const ushort_t* __restrict__ eab,
                                                     const ushort_t* __restrict__ WeT,
                                                     const float* __restrict__ bcat,
                                                     const ushort_t* __restrict__ P,
                                                     ushort_t* __restrict__ hacc) {
    __shared__ ushort_t Qs[64 * 264];   // 33 KB, +8 pad per row
    const int tid = threadIdx.x;
    const int w = tid >> 6, l = tid & 63;
    const int lrow = l & 15, lk = l >> 4;
    const int e0 = blockIdx.x * 64;          // NE % 64 == 0

    // ---- phase 1 ----
    {
        const int tile = w >> 1, half = w & 1;
        f32x4 acc[8];
        #pragma unroll
        for (int i = 0; i < 8; ++i) acc[i] = (f32x4){0.f, 0.f, 0.f, 0.f};
        const int arow = e0 + tile * 16 + lrow;
        const ushort_t* wslice = WeT + (size_t)half * 128 * 64;
        #pragma unroll
        for (int ks = 0; ks < 2; ++ks) {
            int kb = ks * 32 + lk * 8;
            bf16x8 af = *(const bf16x8*)(eab + (size_t)arow * 64 + kb);
            #pragma unroll
            for (int nc = 0; nc < 8; ++nc) {
                bf16x8 bfr = *(const bf16x8*)(wslice + (size_t)(nc * 16 + lrow) * 64 + kb);
                acc[nc] = __builtin_amdgcn_mfma_f32_16x16x32_bf16(af, bfr, acc[nc], 0, 0, 0);
            }
        }
        #pragma unroll
        for (int nc = 0; nc < 8; ++nc) {
            int col = half * 128 + nc * 16 + lrow;
            float bb = bcat[col];
            #pragma unroll
            for (int r = 0; r < 4; ++r) {
                Qs[(tile * 16 + lk * 4 + r) * 264 + col] = f2bf(acc[nc][r] + bb);
            }
        }
    }
    __syncthreads();

    // ---- phase 2 ----
    const int half = l >> 5, l32 = l & 31;
    int dd[4];
    uint2 A[4], B[4], C[4], D[4], QF[4], QS[4];
    #pragma unroll
    for (int i = 0; i < 4; ++i) {
        int j2 = w * 8 + i * 2 + half;     // edge slot within block
        int e = e0 + j2;
        int s = ei[e];                     // source (x_j)
        int d = ei[NE + e];                // target (x_i)
        dd[i] = d;
        const uint2* Pd = (const uint2*)(P + (size_t)d * 512);
        const uint2* Ps = (const uint2*)(P + (size_t)s * 512);
        A[i] = Pd[l32];                    // Wf-dst  cols 4*l32..+3
        B[i] = Ps[32 + l32];               // Wf-src
        C[i] = Pd[64 + l32];               // Ws-dst
        D[i] = Ps[96 + l32];               // Ws-src
        const uint2* qr = (const uint2*)(Qs + (size_t)j2 * 264);
        QF[i] = qr[l32];
        QS[i] = qr[32 + l32];
    }
    #pragma unroll
    for (int i = 0; i < 4; ++i) {
        float2 a0 = upk(A[i].x), a1 = upk(A[i].y);
        float2 b0 = upk(B[i].x), b1 = upk(B[i].y);
        float2 c0 = upk(C[i].x), c1 = upk(C[i].y);
        float2 d0 = upk(D[i].x), d1 = upk(D[i].y);
        float2 qf0 = upk(QF[i].x), qf1 = upk(QF[i].y);
        float2 qs0 = upk(QS[i].x), qs1 = upk(QS[i].y);
        float m0 = msg_act(a0.x + b0.x + qf0.x, c0.x + d0.x + qs0.x);
        float m1 = msg_act(a0.y + b0.y + qf0.y, c0.y + d0.y + qs0.y);
        float m2 = msg_act(a1.x + b1.x + qf1.x, c1.x + d1.x + qs1.x);
        float m3 = msg_act(a1.y + b1.y + qf1.y, c1.y + d1.y + qs1.y);
        unsigned int pk0 = (unsigned int)f2bf(m0) | ((unsigned int)f2bf(m1) << 16);
        unsigned int pk1 = (unsigned int)f2bf(m2) | ((unsigned int)f2bf(m3) << 16);
        unsigned int* addr = (unsigned int*)(hacc + (size_t)dd[i] * 128 + 4 * l32);
        asm volatile("global_atomic_pk_add_bf16 %0, %1, off" :: "v"(addr), "v"(pk0));
        asm volatile("global_atomic_pk_add_bf16 %0, %1, off" :: "v"(addr + 1), "v"(pk1));
    }
}

// hb2 = relu(hb1) on bf16 (sign bit -> zero), 8 elems/thread
__global__ void relu_bf(const ushort_t* __restrict__ in, ushort_t* __restrict__ out, int n8) {
    int i = blockIdx.x * 256 + threadIdx.x;
    if (i >= n8) return;
    uint4 v = ((const uint4*)in)[i];
    unsigned int* pv = (unsigned int*)&v;
    #pragma unroll
    for (int j = 0; j < 4; ++j) {
        unsigned int u = pv[j];
        unsigned int lo = (u & 0x8000u) ? 0u : (u & 0xFFFFu);
        unsigned int hi = (u & 0x80000000u) ? 0u : (u & 0xFFFF0000u);
        pv[j] = lo | hi;
    }
    ((uint4*)out)[i] = v;
}

// out[n] = dot(hb[n,:], Wfc) + bfc ; one wave per node
__global__ __launch_bounds__(256) void final_fc(const ushort_t* __restrict__ hb,
                                                const float* __restrict__ W,
                                                const float* __restrict__ b,
                                                float* __restrict__ out) {
    int gid = blockIdx.x * 256 + threadIdx.x;
    int n = gid >> 6, lane = gid & 63;
    if (n >= NN) return;
    unsigned int hv = ((const unsigned int*)(hb + (size_t)n * 128))[lane];
    float2 h2 = upk(hv);
    float2 wv = ((const float2*)W)[lane];
    float p = h2.x * wv.x + h2.y * wv.y;
    #pragma unroll
    for (int off = 32; off > 0; off >>= 1) p += __shfl_down(p, off);
    if (lane == 0) out[n] = p + b[0];
}

extern "C" void kernel_launch(void* const* d_in, const int* in_sizes, int n_in,
                              void* d_out, int out_size, void* d_ws, size_t ws_size,
                              hipStream_t stream) {
    const float* x   = (const float*)d_in[0];
    const int*   ei  = (const int*)d_in[1];
    const float* ea  = (const float*)d_in[2];
    const float* Wf1 = (const float*)d_in[3];
    const float* bf1 = (const float*)d_in[4];
    const float* Ws1 = (const float*)d_in[5];
    const float* bs1 = (const float*)d_in[6];
    const float* Wf2 = (const float*)d_in[7];
    const float* bf2 = (const float*)d_in[8];
    const float* Ws2 = (const float*)d_in[9];
    const float* bs2 = (const float*)d_in[10];
    const float* Wfc = (const float*)d_in[11];
    const float* bfc = (const float*)d_in[12];
    float* out = (float*)d_out;

    ushort_t* hb1 = (ushort_t*)d_ws;                 // NN*128 bf16
    ushort_t* hb2 = hb1 + (size_t)NN * 128;          // NN*128 bf16
    ushort_t* P   = hb2 + (size_t)NN * 128;          // NN*512 bf16
    ushort_t* eab = P + (size_t)NN * 512;            // NE*64 bf16
    ushort_t* WT  = eab + (size_t)NE * 64;           // 2 x 512*128 bf16
    ushort_t* WeT = WT + 2 * 512 * 128;              // 2 x 256*64 bf16
    float* bcat   = (float*)(WeT + 2 * 256 * 64);    // 2 x 256 f32

    cvt_bf16<<<(NN * 128 / 8 + 255) / 256, 256, 0, stream>>>(x, hb1, NN * 128 / 8);
    cvt_bf16<<<(NE * 64 / 8 + 255) / 256, 256, 0, stream>>>(ea, eab, NE * 64 / 8);
    const int packN = 512 * 128 + 256 * 64 + 256;
    pack_weights<<<(packN + 255) / 256, 256, 0, stream>>>(Wf1, bf1, Ws1, bs1,
                                                          WT, WeT, bcat);
    pack_weights<<<(packN + 255) / 256, 256, 0, stream>>>(Wf2, bf2, Ws2, bs2,
                                                          WT + 512 * 128, WeT + 256 * 64, bcat + 256);

    for (int conv = 0; conv < 2; ++conv) {
        ushort_t* h = conv ? hb2 : hb1;   // GEMM input AND accumulation target
        node_gemm<<<dim3((NN + 63) / 64, 4), 256, 0, stream>>>(h, WT + conv * 512 * 128, P);
        edge_fused<<<NE / 64, 512, 0, stream>>>(ei, eab, WeT + conv * 256 * 64,
                                                bcat + conv * 256, P, h);
        if (conv == 0) {
            relu_bf<<<(NN * 128 / 8 + 255) / 256, 256, 0, stream>>>(hb1, hb2, NN * 128 / 8);
        }
    }
    final_fc<<<((size_t)NN * 64 + 255) / 256, 256, 0, stream>>>(hb2, Wfc, bfc, out);
}

// Round 8
// 370.965 us; speedup vs baseline: 1.3427x; 1.3427x over previous
//
#include <hip/hip_runtime.h>
#include <math.h>

#define NN 50000
#define NE 400000

typedef __attribute__((ext_vector_type(8))) short bf16x8;
typedef __attribute__((ext_vector_type(4))) float f32x4;
typedef unsigned short ushort_t;

__device__ __forceinline__ unsigned short f2bf(float f) {
    unsigned int u = __float_as_uint(f);
    u += 0x7FFF + ((u >> 16) & 1);   // RNE
    return (unsigned short)(u >> 16);
}
__device__ __forceinline__ float2 upk(unsigned int w) {
    float2 r;
    r.x = __uint_as_float(w << 16);
    r.y = __uint_as_float(w & 0xFFFF0000u);
    return r;
}

#define LOG2E 1.4426950408889634f
#define LN2   0.6931471805599453f

// msg = sigmoid(gf)*softplus(gs) via raw v_exp_f32/v_log_f32/v_rcp_f32.
// Valid since |g| << 127: exp2 cannot overflow, both tails exact in fp32.
__device__ __forceinline__ float msg_act(float gf, float gs) {
    float tf = __builtin_amdgcn_exp2f(gf * -LOG2E);
    float sig = __builtin_amdgcn_rcpf(1.0f + tf) * LN2;   // sigmoid * ln2
    float ts = __builtin_amdgcn_exp2f(gs * LOG2E);
    float lg = __builtin_amdgcn_logf(1.0f + ts);          // log2(1+2^(s*log2e))
    return sig * lg;
}

// WT[512][128]: row c = output col, contiguous k. cols 0-127 Wf(dst), 128-255 Wf(src),
// 256-383 Ws(dst), 384-511 Ws(src). WeT[256][64] same for edge part. bcat=[bf|bs].
__global__ void pack_weights(const float* __restrict__ Wf, const float* __restrict__ bf,
                             const float* __restrict__ Ws, const float* __restrict__ bs,
                             ushort_t* __restrict__ WT, ushort_t* __restrict__ WeT,
                             float* __restrict__ bcat) {
    int i = blockIdx.x * 256 + threadIdx.x;
    if (i < 512 * 128) {
        int c = i >> 7, k = i & 127;
        float w;
        if (c < 128)      w = Wf[k * 128 + c];
        else if (c < 256) w = Wf[(128 + k) * 128 + (c - 128)];
        else if (c < 384) w = Ws[k * 128 + (c - 256)];
        else              w = Ws[(128 + k) * 128 + (c - 384)];
        WT[i] = f2bf(w);
    } else if (i < 512 * 128 + 256 * 64) {
        int j = i - 512 * 128;
        int c = j >> 6, k = j & 63;
        float w = (c < 128) ? Wf[(256 + k) * 128 + c] : Ws[(256 + k) * 128 + (c - 128)];
        WeT[j] = f2bf(w);
    } else if (i < 512 * 128 + 256 * 64 + 256) {
        int c = i - (512 * 128 + 256 * 64);
        bcat[c] = (c < 128) ? bf[c] : bs[c - 128];
    }
}

// fp32 -> bf16 bulk convert, 8 elems/thread
__global__ void cvt_bf16(const float* __restrict__ in, ushort_t* __restrict__ out, int n8) {
    int i = blockIdx.x * 256 + threadIdx.x;
    if (i >= n8) return;
    const float4* p = (const float4*)in + (size_t)i * 2;
    float4 a = p[0], b = p[1];
    bf16x8 v;
    v[0] = (short)f2bf(a.x); v[1] = (short)f2bf(a.y);
    v[2] = (short)f2bf(a.z); v[3] = (short)f2bf(a.w);
    v[4] = (short)f2bf(b.x); v[5] = (short)f2bf(b.y);
    v[6] = (short)f2bf(b.z); v[7] = (short)f2bf(b.w);
    *((bf16x8*)out + i) = v;
}

// P[NN][512] (bf16) = hb[NN][128] (bf16) @ W. Grid (ceil(NN/64), 4); 4 waves/block.
__global__ __launch_bounds__(256) void node_gemm(const ushort_t* __restrict__ hb,
                                                 const ushort_t* __restrict__ WT,
                                                 ushort_t* __restrict__ P) {
    __shared__ ushort_t Bs[128 * 136];
    const int tid = threadIdx.x;
    const int w = tid >> 6, l = tid & 63;
    const int by = blockIdx.y;
    const ushort_t* src = WT + (size_t)by * 128 * 128;
    #pragma unroll
    for (int j = 0; j < 8; ++j) {
        int cid = j * 256 + tid;            // 2048 chunks of 8 bf16
        int row = cid >> 4, off = (cid & 15) * 8;
        *(bf16x8*)(&Bs[row * 136 + off]) = *(const bf16x8*)(src + row * 128 + off);
    }
    __syncthreads();
    const int r0 = blockIdx.x * 64 + w * 16;
    const int lrow = l & 15, lk = l >> 4;
    int arow = r0 + lrow;
    if (arow >= NN) arow = NN - 1;
    f32x4 acc[8];
    #pragma unroll
    for (int i = 0; i < 8; ++i) acc[i] = (f32x4){0.f, 0.f, 0.f, 0.f};
    #pragma unroll
    for (int ks = 0; ks < 4; ++ks) {
        int kb = ks * 32 + lk * 8;
        bf16x8 af = *(const bf16x8*)(hb + (size_t)arow * 128 + kb);
        #pragma unroll
        for (int nc = 0; nc < 8; ++nc) {
            bf16x8 bfr = *(const bf16x8*)(&Bs[(nc * 16 + lrow) * 136 + kb]);
            acc[nc] = __builtin_amdgcn_mfma_f32_16x16x32_bf16(af, bfr, acc[nc], 0, 0, 0);
        }
    }
    const int rb = r0 + lk * 4;
    const int cb = by * 128;
    #pragma unroll
    for (int nc = 0; nc < 8; ++nc) {
        int col = cb + nc * 16 + lrow;
        #pragma unroll
        for (int r = 0; r < 4; ++r) {
            int row = rb + r;
            if (row < NN) P[(size_t)row * 512 + col] = f2bf(acc[nc][r]);
        }
    }
}

// Fused: 512 threads / block = 8 waves; block owns 64 consecutive edges.
// Phase 1: wave-pair (tile = w>>1, half = w&1) computes Q[tile*16..+16][half*128..+128]
//          = eab @ We + b via 8 MFMAs -> LDS (bf16, rows padded to 264).
// Phase 2: wave w handles edges w*8..w*8+7. ALL 48 gathers issued first, then a
//          sched_barrier(0) pins them (loads cannot sink past it), then compute +
//          one packed-bf16 atomic per lane per edge. Waits become counted vmcnt(N).
__global__ __launch_bounds__(512, 2) void edge_fused(const int* __restrict__ ei,
                                                     const ushort_t* __restrict__ eab,
                                                     const ushort_t* __restrict__ WeT,
                                                     const float* __restrict__ bcat,
                                                     const ushort_t* __restrict__ P,
                                                     ushort_t* __restrict__ hacc) {
    __shared__ ushort_t Qs[64 * 264];   // 33 KB, +8 pad per row
    const int tid = threadIdx.x;
    const int w = tid >> 6, l = tid & 63;
    const int lrow = l & 15, lk = l >> 4;
    const int e0 = blockIdx.x * 64;          // NE % 64 == 0

    // ---- phase 1 ----
    {
        const int tile = w >> 1, half = w & 1;
        f32x4 acc[8];
        #pragma unroll
        for (int i = 0; i < 8; ++i) acc[i] = (f32x4){0.f, 0.f, 0.f, 0.f};
        const int arow = e0 + tile * 16 + lrow;
        const ushort_t* wslice = WeT + (size_t)half * 128 * 64;
        #pragma unroll
        for (int ks = 0; ks < 2; ++ks) {
            int kb = ks * 32 + lk * 8;
            bf16x8 af = *(const bf16x8*)(eab + (size_t)arow * 64 + kb);
            #pragma unroll
            for (int nc = 0; nc < 8; ++nc) {
                bf16x8 bfr = *(const bf16x8*)(wslice + (size_t)(nc * 16 + lrow) * 64 + kb);
                acc[nc] = __builtin_amdgcn_mfma_f32_16x16x32_bf16(af, bfr, acc[nc], 0, 0, 0);
            }
        }
        #pragma unroll
        for (int nc = 0; nc < 8; ++nc) {
            int col = half * 128 + nc * 16 + lrow;
            float bb = bcat[col];
            #pragma unroll
            for (int r = 0; r < 4; ++r) {
                Qs[(tile * 16 + lk * 4 + r) * 264 + col] = f2bf(acc[nc][r] + bb);
            }
        }
    }
    __syncthreads();

    // ---- phase 2: issue all gathers for 8 edges, pin with sched_barrier, compute ----
    int dd[8];
    unsigned int A[8], B[8], C[8], D[8], QF[8], QS[8];
    #pragma unroll
    for (int i = 0; i < 8; ++i) {
        int j = w * 8 + i;
        int e = e0 + j;
        int s = ei[e];                     // source (x_j)
        int d = ei[NE + e];                // target (x_i)
        dd[i] = d;
        const unsigned int* Pd = (const unsigned int*)(P + (size_t)d * 512);
        const unsigned int* Ps = (const unsigned int*)(P + (size_t)s * 512);
        A[i] = Pd[l];                      // Wf-dst
        B[i] = Ps[64 + l];                 // Wf-src
        C[i] = Pd[128 + l];                // Ws-dst
        D[i] = Ps[192 + l];                // Ws-src
        const unsigned int* qr = (const unsigned int*)(Qs + (size_t)j * 264);
        QF[i] = qr[l];
        QS[i] = qr[64 + l];
    }
    __builtin_amdgcn_sched_barrier(0);     // loads may not sink below this point
    #pragma unroll
    for (int i = 0; i < 8; ++i) {
        float2 af_ = upk(A[i]);
        float2 bf_ = upk(B[i]);
        float2 as_ = upk(C[i]);
        float2 bs_ = upk(D[i]);
        float2 qf = upk(QF[i]);
        float2 qs = upk(QS[i]);
        float m0 = msg_act(af_.x + bf_.x + qf.x, as_.x + bs_.x + qs.x);
        float m1 = msg_act(af_.y + bf_.y + qf.y, as_.y + bs_.y + qs.y);
        unsigned int pk = (unsigned int)f2bf(m0) | ((unsigned int)f2bf(m1) << 16);
        unsigned int* addr = (unsigned int*)(hacc + (size_t)dd[i] * 128 + 2 * l);
        asm volatile("global_atomic_pk_add_bf16 %0, %1, off" :: "v"(addr), "v"(pk));
    }
}

// hb2 = relu(hb1) on bf16 (sign bit -> zero), 8 elems/thread
__global__ void relu_bf(const ushort_t* __restrict__ in, ushort_t* __restrict__ out, int n8) {
    int i = blockIdx.x * 256 + threadIdx.x;
    if (i >= n8) return;
    uint4 v = ((const uint4*)in)[i];
    unsigned int* pv = (unsigned int*)&v;
    #pragma unroll
    for (int j = 0; j < 4; ++j) {
        unsigned int u = pv[j];
        unsigned int lo = (u & 0x8000u) ? 0u : (u & 0xFFFFu);
        unsigned int hi = (u & 0x80000000u) ? 0u : (u & 0xFFFF0000u);
        pv[j] = lo | hi;
    }
    ((uint4*)out)[i] = v;
}

// out[n] = dot(hb[n,:], Wfc) + bfc ; one wave per node
__global__ __launch_bounds__(256) void final_fc(const ushort_t* __restrict__ hb,
                                                const float* __restrict__ W,
                                                const float* __restrict__ b,
                                                float* __restrict__ out) {
    int gid = blockIdx.x * 256 + threadIdx.x;
    int n = gid >> 6, lane = gid & 63;
    if (n >= NN) return;
    unsigned int hv = ((const unsigned int*)(hb + (size_t)n * 128))[lane];
    float2 h2 = upk(hv);
    float2 wv = ((const float2*)W)[lane];
    float p = h2.x * wv.x + h2.y * wv.y;
    #pragma unroll
    for (int off = 32; off > 0; off >>= 1) p += __shfl_down(p, off);
    if (lane == 0) out[n] = p + b[0];
}

extern "C" void kernel_launch(void* const* d_in, const int* in_sizes, int n_in,
                              void* d_out, int out_size, void* d_ws, size_t ws_size,
                              hipStream_t stream) {
    const float* x   = (const float*)d_in[0];
    const int*   ei  = (const int*)d_in[1];
    const float* ea  = (const float*)d_in[2];
    const float* Wf1 = (const float*)d_in[3];
    const float* bf1 = (const float*)d_in[4];
    const float* Ws1 = (const float*)d_in[5];
    const float* bs1 = (const float*)d_in[6];
    const float* Wf2 = (const float*)d_in[7];
    const float* bf2 = (const float*)d_in[8];
    const float* Ws2 = (const float*)d_in[9];
    const float* bs2 = (const float*)d_in[10];
    const float* Wfc = (const float*)d_in[11];
    const float* bfc = (const float*)d_in[12];
    float* out = (float*)d_out;

    ushort_t* hb1 = (ushort_t*)d_ws;                 // NN*128 bf16
    ushort_t* hb2 = hb1 + (size_t)NN * 128;          // NN*128 bf16
    ushort_t* P   = hb2 + (size_t)NN * 128;          // NN*512 bf16
    ushort_t* eab = P + (size_t)NN * 512;            // NE*64 bf16
    ushort_t* WT  = eab + (size_t)NE * 64;           // 2 x 512*128 bf16
    ushort_t* WeT = WT + 2 * 512 * 128;              // 2 x 256*64 bf16
    float* bcat   = (float*)(WeT + 2 * 256 * 64);    // 2 x 256 f32

    cvt_bf16<<<(NN * 128 / 8 + 255) / 256, 256, 0, stream>>>(x, hb1, NN * 128 / 8);
    cvt_bf16<<<(NE * 64 / 8 + 255) / 256, 256, 0, stream>>>(ea, eab, NE * 64 / 8);
    const int packN = 512 * 128 + 256 * 64 + 256;
    pack_weights<<<(packN + 255) / 256, 256, 0, stream>>>(Wf1, bf1, Ws1, bs1,
                                                          WT, WeT, bcat);
    pack_weights<<<(packN + 255) / 256, 256, 0, stream>>>(Wf2, bf2, Ws2, bs2,
                                                          WT + 512 * 128, WeT + 256 * 64, bcat + 256);

    for (int conv = 0; conv < 2; ++conv) {
        ushort_t* h = conv ? hb2 : hb1;   // GEMM input AND accumulation target
        node_gemm<<<dim3((NN + 63) / 64, 4), 256, 0, stream>>>(h, WT + conv * 512 * 128, P);
        edge_fused<<<NE / 64, 512, 0, stream>>>(ei, eab, WeT + conv * 256 * 64,
                                                bcat + conv * 256, P, h);
        if (conv == 0) {
            relu_bf<<<(NN * 128 / 8 + 255) / 256, 256, 0, stream>>>(hb1, hb2, NN * 128 / 8);
        }
    }
    final_fc<<<((size_t)NN * 64 + 255) / 256, 256, 0, stream>>>(hb2, Wfc, bfc, out);
}